// Round 2
// 386.025 us; speedup vs baseline: 1.0573x; 1.0573x over previous
//
#include <hip/hip_runtime.h>
#include <cstdint>

#define NH 16
#define DH 64
#define FF 4096
#define PP 512
#define BB 2048

typedef __bf16 bf16x8 __attribute__((ext_vector_type(8)));
typedef float f32x4 __attribute__((ext_vector_type(4)));
typedef float fl4 __attribute__((ext_vector_type(4)));
typedef unsigned short us4 __attribute__((ext_vector_type(4)));
typedef unsigned int u32x2 __attribute__((ext_vector_type(2)));

__device__ __forceinline__ unsigned short f2bf(float f) {
  unsigned u = __float_as_uint(f);
  u += 0x7FFFu + ((u >> 16) & 1u);
  return (unsigned short)(u >> 16);
}

// pack two f32 -> two bf16 (round-half-up: +0x8000, take high16s via v_perm)
__device__ __forceinline__ unsigned int pkbf(float lo, float hi) {
  unsigned a = __float_as_uint(lo) + 0x8000u;
  unsigned b = __float_as_uint(hi) + 0x8000u;
  return __builtin_amdgcn_perm(b, a, 0x07060302u);
}

// async global->LDS, 16B/lane. LDS dest = wave-uniform base + lane*16;
// global source is per-lane arbitrary (exploited for the XOR swizzle).
__device__ __forceinline__ void gload_lds16(const void* g, void* l) {
  __builtin_amdgcn_global_load_lds(
      (const __attribute__((address_space(1))) void*)g,
      (__attribute__((address_space(3))) void*)(unsigned int)(unsigned long long)l,
      16, 0, 0);
}

// convert features + prototypes fp32 -> bf16 (x is consumed fp32 directly)
__global__ void cvt_fp(const float* __restrict__ f, const float* __restrict__ p,
                       unsigned short* __restrict__ fb,
                       unsigned short* __restrict__ pb) {
  const int nf = FF * 1024 / 4, np = PP * 1024 / 4;
  int i = blockIdx.x * blockDim.x + threadIdx.x;
  const fl4* src;
  us4* dst;
  if (i < nf) {
    src = (const fl4*)f + i;
    dst = (us4*)fb + i;
  } else if (i < nf + np) {
    src = (const fl4*)p + (i - nf);
    dst = (us4*)pb + (i - nf);
  } else {
    return;
  }
  fl4 v = *src;
  us4 o;
  o.x = f2bf(v.x); o.y = f2bf(v.y); o.z = f2bf(v.z); o.w = f2bf(v.w);
  *dst = o;
}

// ---------------------------------------------------------------------------
// Phase 1: per-head [P x F, K=64] GEMM on prototypes.
//   Q1 = th*Pw + al*Pp - al,  Q2 = be*Pw   (layout [h][p][f], bf16)
//   pws[h][p] += be * sum_f Pw
// ---------------------------------------------------------------------------
__global__ __launch_bounds__(256, 2) void gemm_proto(
    const unsigned short* __restrict__ Abf, const unsigned short* __restrict__ Fbf,
    unsigned short* __restrict__ O1, unsigned short* __restrict__ O2,
    float* __restrict__ pws,
    const float* __restrict__ theta, const float* __restrict__ alpha,
    const float* __restrict__ beta) {
  const int h = blockIdx.z;
  const int n0 = blockIdx.x * 128;   // f tile
  const int lm0 = blockIdx.y * 128;  // p tile
  const int t = threadIdx.x;

  __shared__ __align__(16) char As[128 * 128];
  __shared__ __align__(16) char Bs[128 * 128];

  {
    const char* ab = (const char*)(Abf + (size_t)lm0 * 1024 + h * 64);
    const char* bb = (const char*)(Fbf + (size_t)n0 * 1024 + h * 64);
#pragma unroll
    for (int r = 0; r < 4; ++r) {
      int o = r * 4096 + t * 16;
      int row = o >> 7, col = o & 127;
      gload_lds16(ab + (size_t)row * 2048 + col, As + o);
      gload_lds16(bb + (size_t)row * 2048 + col, Bs + o);
    }
  }
  __syncthreads();

  const int wave = t >> 6, lane = t & 63;
  const int wm = wave & 1, wn = wave >> 1;
  const int quad = lane >> 4, lr = lane & 15;

  f32x4 acc[4][4];
#pragma unroll
  for (int i = 0; i < 4; ++i)
#pragma unroll
    for (int j = 0; j < 4; ++j) acc[i][j] = (f32x4){0.f, 0.f, 0.f, 0.f};

#pragma unroll
  for (int s = 0; s < 2; ++s) {
    bf16x8 av[4], bv[4];
#pragma unroll
    for (int fm = 0; fm < 4; ++fm) {
      int row = wm * 64 + fm * 16 + lr;
      av[fm] = *(const bf16x8*)(As + row * 128 + s * 64 + quad * 16);
    }
#pragma unroll
    for (int fn = 0; fn < 4; ++fn) {
      int row = wn * 64 + fn * 16 + lr;
      bv[fn] = *(const bf16x8*)(Bs + row * 128 + s * 64 + quad * 16);
    }
#pragma unroll
    for (int fm = 0; fm < 4; ++fm)
#pragma unroll
      for (int fn = 0; fn < 4; ++fn)
        acc[fm][fn] = __builtin_amdgcn_mfma_f32_16x16x32_bf16(av[fm], bv[fn],
                                                              acc[fm][fn], 0, 0, 0);
  }

  const float th = theta[h], al = alpha[h], be = beta[h];

#pragma unroll
  for (int fm = 0; fm < 4; ++fm) {
    int prow = lm0 + wm * 64 + fm * 16 + quad * 4;
    float rs0 = 0.f, rs1 = 0.f, rs2 = 0.f, rs3 = 0.f;
#pragma unroll
    for (int fn = 0; fn < 4; ++fn) {
      int f = n0 + wn * 64 + fn * 16 + lr;
#pragma unroll
      for (int i = 0; i < 4; ++i) {
        float pf = acc[fm][fn][i];
        float pp = fmaxf(pf, 0.f);
        float pw = pf * pp;
        size_t idx = ((size_t)(h * PP + prow + i)) * FF + f;
        O1[idx] = f2bf(th * pw + al * pp - al);
        O2[idx] = f2bf(be * pw);
        if (i == 0) rs0 += pw;
        else if (i == 1) rs1 += pw;
        else if (i == 2) rs2 += pw;
        else rs3 += pw;
      }
    }
    float rs[4] = {rs0, rs1, rs2, rs3};
#pragma unroll
    for (int i = 0; i < 4; ++i) {
      float s = rs[i];
      s += __shfl_xor(s, 1);
      s += __shfl_xor(s, 2);
      s += __shfl_xor(s, 4);
      s += __shfl_xor(s, 8);
      if (lr == 0) atomicAdd(&pws[h * PP + prow + i], be * s);
    }
  }
}

// ---------------------------------------------------------------------------
// Fused main, round-6 structure + round-7 race fix.
//   - Q1/Q2 fragments load straight into registers (B-operands of MFMA),
//     wave->output decomposition 1x4. Compiler inserts COUNTED vmcnt waits
//     before step D -- no barrier drain of the VMEM queue.
//   - Only sF (4KB/iter) stages via global_load_lds; double-buffered, issued
//     as the NEWEST vmem so the q-register waits never drain it.
//   - RACE FIX (round 7): waitcnt + s_barrier fused into a SINGLE asm block.
//     Raw __builtin_amdgcn_s_barrier() is not a compiler memory fence; with
//     separate asm("s_waitcnt ...") the scheduler could place a cross-wave
//     LDS read in the gap between the wait and the barrier -> intermittent
//     corruption under replay timing (round-1 post-timing divergence).
// LDS = 8 (sF x2) + 8 + 8 = 24 KB; 2 blocks/CU.
// ---------------------------------------------------------------------------
__global__ __launch_bounds__(256, 2) void fused_main(
    const float* __restrict__ x, const unsigned short* __restrict__ f_bf,
    const unsigned short* __restrict__ Q1, const unsigned short* __restrict__ Q2,
    const float* __restrict__ pws, float* __restrict__ out) {
  const int h = blockIdx.z;
  const int n0 = blockIdx.x * 256;  // p tile
  const int m0 = blockIdx.y * 128;  // b tile
  const int t = threadIdx.x;
  const int wave = t >> 6, lane = t & 63;
  const int quad = lane >> 4, lr = lane & 15;
  const int key8 = lr & 7;         // swizzle key for 128B-row buffer (sF)
  const int key2 = (lr >> 1) & 3;  // swizzle key for 64B-row buffers (sX*)

  __shared__ __align__(16) char sF[2 * 4096];
  __shared__ __align__(16) char sXw[8192];
  __shared__ __align__(16) char sXp[8192];

  // Xh B-operand fragments, loaded fp32 and packed in-register.
  bf16x8 xh[2][2];
#pragma unroll
  for (int bn = 0; bn < 2; ++bn)
#pragma unroll
    for (int s = 0; s < 2; ++s) {
      int b = m0 + wave * 32 + bn * 16 + lr;
      const float* xr = x + (size_t)b * 1024 + h * 64 + s * 32 + quad * 8;
      fl4 v0 = *(const fl4*)xr;
      fl4 v1 = *(const fl4*)(xr + 4);
      union { unsigned u[4]; bf16x8 v; } cv;
      cv.u[0] = pkbf(v0.x, v0.y);
      cv.u[1] = pkbf(v0.z, v0.w);
      cv.u[2] = pkbf(v1.x, v1.y);
      cv.u[3] = pkbf(v1.z, v1.w);
      xh[bn][s] = cv.v;
    }

  // ---- hoisted (loop-invariant) LDS byte offsets ----
  int af_off[2][2];  // step B reads: sF row fm*16+lr, global chunk s*4+quad
#pragma unroll
  for (int fm = 0; fm < 2; ++fm)
#pragma unroll
    for (int s = 0; s < 2; ++s)
      af_off[fm][s] = (fm * 16 + lr) * 128 + (((s * 4 + quad) ^ key8) * 16);

  int cw_off[2][2];  // step C writes: row wave*32+bn*16+lr, chunk fm*2+(quad>>1)
#pragma unroll
  for (int fm = 0; fm < 2; ++fm)
#pragma unroll
    for (int bn = 0; bn < 2; ++bn)
      cw_off[fm][bn] = (wave * 32 + bn * 16 + lr) * 64 +
                       (((fm * 2 + (quad >> 1)) ^ key2) * 16) + (quad & 1) * 8;

  int aw_off[8];  // step D A reads: row fm*16+lr (all 128 b rows), chunk quad
#pragma unroll
  for (int fm = 0; fm < 8; ++fm)
    aw_off[fm] = (fm * 16 + lr) * 64 + ((quad ^ key2) * 16);

  // sF staging source (swizzle applied on the GLOBAL side)
  const char* srcF;
  {
    int row = t >> 3, c = t & 7, cs = c ^ (row & 7);
    srcF = (const char*)f_bf + h * 128 + (size_t)row * 2048 + cs * 16;
  }

  // per-wave Q row pointers: wave owns p = n0 + wave*64 .. +63
  const unsigned short* qrow1 =
      Q1 + (size_t)(h * PP + n0 + wave * 64 + lr) * FF + quad * 8;
  const unsigned short* qrow2 =
      Q2 + (size_t)(h * PP + n0 + wave * 64 + lr) * FF + quad * 8;

  f32x4 acc[8][4];
#pragma unroll
  for (int i = 0; i < 8; ++i)
#pragma unroll
    for (int j = 0; j < 4; ++j) acc[i][j] = (f32x4){0.f, 0.f, 0.f, 0.f};

  // prologue: stage sF buf0 for it=0
  gload_lds16(srcF, sF + t * 16);
  srcF += 32 * 2048;
  asm volatile("s_waitcnt vmcnt(0)\n\ts_barrier" ::: "memory");
  __builtin_amdgcn_sched_barrier(0);

  for (int it = 0; it < FF / 32; ++it) {
    const int cur = (it & 1) << 12;

    // Q fragment loads for THIS iteration (oldest VMEM of the iteration --
    // step D's compiler-inserted counted vmcnt wait covers exactly these)
    bf16x8 q1v[4], q2v[4];
#pragma unroll
    for (int fn = 0; fn < 4; ++fn) {
      q1v[fn] = *(const bf16x8*)(qrow1 + fn * (16 * FF));
      q2v[fn] = *(const bf16x8*)(qrow2 + fn * (16 * FF));
    }
    qrow1 += 32;
    qrow2 += 32;

    // next-tile F staging (newest VMEM -> stays in flight until end barrier;
    // f_bf is padded by 32 rows so the final iteration's read is in-bounds)
    gload_lds16(srcF, sF + (cur ^ 4096) + t * 16);
    srcF += 32 * 2048;

    // step B: Xf[f 0..31][b wave*32..+31]
    f32x4 xf[2][2];
#pragma unroll
    for (int fm = 0; fm < 2; ++fm)
#pragma unroll
      for (int bn = 0; bn < 2; ++bn) xf[fm][bn] = (f32x4){0.f, 0.f, 0.f, 0.f};
#pragma unroll
    for (int s = 0; s < 2; ++s)
#pragma unroll
      for (int fm = 0; fm < 2; ++fm) {
        bf16x8 af = *(const bf16x8*)(sF + cur + af_off[fm][s]);
#pragma unroll
        for (int bn = 0; bn < 2; ++bn)
          xf[fm][bn] = __builtin_amdgcn_mfma_f32_16x16x32_bf16(af, xh[bn][s],
                                                               xf[fm][bn], 0, 0, 0);
      }

    // step C: transform + pack (lane holds f = fm*16+quad*4+i, b = wave*32+bn*16+lr)
#pragma unroll
    for (int fm = 0; fm < 2; ++fm)
#pragma unroll
      for (int bn = 0; bn < 2; ++bn) {
        float v0 = xf[fm][bn][0], v1 = xf[fm][bn][1];
        float v2 = xf[fm][bn][2], v3 = xf[fm][bn][3];
        float p0 = fmaxf(v0, 0.f), p1 = fmaxf(v1, 0.f);
        float p2 = fmaxf(v2, 0.f), p3 = fmaxf(v3, 0.f);
        u32x2 w, p;
        w.x = pkbf(v0 * p0, v1 * p1);
        w.y = pkbf(v2 * p2, v3 * p3);
        p.x = pkbf(p0, p1);
        p.y = pkbf(p2, p3);
        *(u32x2*)(sXw + cw_off[fm][bn]) = w;
        *(u32x2*)(sXp + cw_off[fm][bn]) = p;
      }
    // fused wait+barrier: no scheduler gap (round-7 race fix)
    asm volatile("s_waitcnt lgkmcnt(0)\n\ts_barrier" ::: "memory");
    __builtin_amdgcn_sched_barrier(0);

    // step D: acc += Xw.Q1^T + Xp.Q2^T  (A from LDS, B from registers)
    __builtin_amdgcn_s_setprio(1);
#pragma unroll
    for (int hf = 0; hf < 2; ++hf) {
      bf16x8 aw[4], ap[4];
#pragma unroll
      for (int fm = 0; fm < 4; ++fm) {
        aw[fm] = *(const bf16x8*)(sXw + aw_off[hf * 4 + fm]);
        ap[fm] = *(const bf16x8*)(sXp + aw_off[hf * 4 + fm]);
      }
#pragma unroll
      for (int fn = 0; fn < 4; ++fn)
#pragma unroll
        for (int fm = 0; fm < 4; ++fm) {
          acc[hf * 4 + fm][fn] = __builtin_amdgcn_mfma_f32_16x16x32_bf16(
              aw[fm], q1v[fn], acc[hf * 4 + fm][fn], 0, 0, 0);
          acc[hf * 4 + fm][fn] = __builtin_amdgcn_mfma_f32_16x16x32_bf16(
              ap[fm], q2v[fn], acc[hf * 4 + fm][fn], 0, 0, 0);
        }
    }
    __builtin_amdgcn_s_setprio(0);

    // end barrier: only the tiny sF stage can still be outstanding here
    // (q loads were consumed in D); protects sXw/sXp overwrite + sF[nxt].
    asm volatile("s_waitcnt vmcnt(0)\n\ts_barrier" ::: "memory");
    __builtin_amdgcn_sched_barrier(0);
  }

  // epilogue: subtract pws, store fp32
#pragma unroll
  for (int fn = 0; fn < 4; ++fn) {
    int p = n0 + wave * 64 + fn * 16 + lr;
    float sub = pws[h * PP + p];
#pragma unroll
    for (int fm = 0; fm < 8; ++fm) {
      int brow = m0 + fm * 16 + quad * 4;
#pragma unroll
      for (int i = 0; i < 4; ++i) {
        out[(size_t)(brow + i) * (NH * PP) + h * PP + p] = acc[fm][fn][i] - sub;
      }
    }
  }
}

extern "C" void kernel_launch(void* const* d_in, const int* in_sizes, int n_in,
                              void* d_out, int out_size, void* d_ws, size_t ws_size,
                              hipStream_t stream) {
  const float* x = (const float*)d_in[0];
  const float* features = (const float*)d_in[1];
  const float* prototypes = (const float*)d_in[2];
  const float* theta = (const float*)d_in[3];
  const float* alpha = (const float*)d_in[4];
  const float* beta = (const float*)d_in[5];
  float* out = (float*)d_out;

  char* ws = (char*)d_ws;
  size_t off = 0;
  auto carve = [&](size_t bytes) -> char* {
    char* p = ws + off;
    off += (bytes + 255) & ~(size_t)255;
    return p;
  };
  // f_bf padded by 32 rows: fused_main's last iteration prefetches one tile
  // past the end (data unused; keeps the main loop branch-free).
  unsigned short* f_bf = (unsigned short*)carve((size_t)(FF + 32) * 1024 * 2);
  unsigned short* p_bf = (unsigned short*)carve((size_t)PP * 1024 * 2);
  unsigned short* Q1 = (unsigned short*)carve((size_t)NH * PP * FF * 2);
  unsigned short* Q2 = (unsigned short*)carve((size_t)NH * PP * FF * 2);
  float* pws = (float*)carve((size_t)NH * PP * 4);

  const int ncvt = (FF + PP) * 1024 / 4;
  cvt_fp<<<(ncvt + 255) / 256, 256, 0, stream>>>(features, prototypes, f_bf, p_bf);
  hipMemsetAsync(pws, 0, (size_t)NH * PP * 4, stream);

  // Phase 1: prototypes -> Q1, Q2, pws
  gemm_proto<<<dim3(FF / 128, PP / 128, NH), 256, 0, stream>>>(
      p_bf, f_bf, Q1, Q2, pws, theta, alpha, beta);

  // Fused main GEMM
  fused_main<<<dim3(PP / 256, BB / 128, NH), 256, 0, stream>>>(
      x, f_bf, Q1, Q2, pws, out);
}

// Round 3
// 383.818 us; speedup vs baseline: 1.0634x; 1.0057x over previous
//
#include <hip/hip_runtime.h>
#include <cstdint>

#define NH 16
#define DH 64
#define FF 4096
#define PP 512
#define BB 2048

typedef __bf16 bf16x8 __attribute__((ext_vector_type(8)));
typedef float f32x4 __attribute__((ext_vector_type(4)));
typedef float fl4 __attribute__((ext_vector_type(4)));
typedef unsigned short us4 __attribute__((ext_vector_type(4)));
typedef unsigned int u32x2 __attribute__((ext_vector_type(2)));

__device__ __forceinline__ unsigned short f2bf(float f) {
  unsigned u = __float_as_uint(f);
  u += 0x7FFFu + ((u >> 16) & 1u);
  return (unsigned short)(u >> 16);
}

// pack two f32 -> two bf16 (round-half-up: +0x8000, take high16s via v_perm)
__device__ __forceinline__ unsigned int pkbf(float lo, float hi) {
  unsigned a = __float_as_uint(lo) + 0x8000u;
  unsigned b = __float_as_uint(hi) + 0x8000u;
  return __builtin_amdgcn_perm(b, a, 0x07060302u);
}

// async global->LDS, 16B/lane. LDS dest = wave-uniform base + lane*16;
// global source is per-lane arbitrary (exploited for the XOR swizzle).
__device__ __forceinline__ void gload_lds16(const void* g, void* l) {
  __builtin_amdgcn_global_load_lds(
      (const __attribute__((address_space(1))) void*)g,
      (__attribute__((address_space(3))) void*)(unsigned int)(unsigned long long)l,
      16, 0, 0);
}

// convert features + prototypes fp32 -> bf16 (x is consumed fp32 directly)
__global__ void cvt_fp(const float* __restrict__ f, const float* __restrict__ p,
                       unsigned short* __restrict__ fb,
                       unsigned short* __restrict__ pb) {
  const int nf = FF * 1024 / 4, np = PP * 1024 / 4;
  int i = blockIdx.x * blockDim.x + threadIdx.x;
  const fl4* src;
  us4* dst;
  if (i < nf) {
    src = (const fl4*)f + i;
    dst = (us4*)fb + i;
  } else if (i < nf + np) {
    src = (const fl4*)p + (i - nf);
    dst = (us4*)pb + (i - nf);
  } else {
    return;
  }
  fl4 v = *src;
  us4 o;
  o.x = f2bf(v.x); o.y = f2bf(v.y); o.z = f2bf(v.z); o.w = f2bf(v.w);
  *dst = o;
}

// ---------------------------------------------------------------------------
// Phase 1: per-head [P x F, K=64] GEMM on prototypes.
//   Q1 = th*Pw + al*Pp - al,  Q2 = be*Pw   (layout [h][p][f], bf16)
//   pws[h][p] += be * sum_f Pw
// ---------------------------------------------------------------------------
__global__ __launch_bounds__(256, 2) void gemm_proto(
    const unsigned short* __restrict__ Abf, const unsigned short* __restrict__ Fbf,
    unsigned short* __restrict__ O1, unsigned short* __restrict__ O2,
    float* __restrict__ pws,
    const float* __restrict__ theta, const float* __restrict__ alpha,
    const float* __restrict__ beta) {
  const int h = blockIdx.z;
  const int n0 = blockIdx.x * 128;   // f tile
  const int lm0 = blockIdx.y * 128;  // p tile
  const int t = threadIdx.x;

  __shared__ __align__(16) char As[128 * 128];
  __shared__ __align__(16) char Bs[128 * 128];

  {
    const char* ab = (const char*)(Abf + (size_t)lm0 * 1024 + h * 64);
    const char* bb = (const char*)(Fbf + (size_t)n0 * 1024 + h * 64);
#pragma unroll
    for (int r = 0; r < 4; ++r) {
      int o = r * 4096 + t * 16;
      int row = o >> 7, col = o & 127;
      gload_lds16(ab + (size_t)row * 2048 + col, As + o);
      gload_lds16(bb + (size_t)row * 2048 + col, Bs + o);
    }
  }
  __syncthreads();

  const int wave = t >> 6, lane = t & 63;
  const int wm = wave & 1, wn = wave >> 1;
  const int quad = lane >> 4, lr = lane & 15;

  f32x4 acc[4][4];
#pragma unroll
  for (int i = 0; i < 4; ++i)
#pragma unroll
    for (int j = 0; j < 4; ++j) acc[i][j] = (f32x4){0.f, 0.f, 0.f, 0.f};

#pragma unroll
  for (int s = 0; s < 2; ++s) {
    bf16x8 av[4], bv[4];
#pragma unroll
    for (int fm = 0; fm < 4; ++fm) {
      int row = wm * 64 + fm * 16 + lr;
      av[fm] = *(const bf16x8*)(As + row * 128 + s * 64 + quad * 16);
    }
#pragma unroll
    for (int fn = 0; fn < 4; ++fn) {
      int row = wn * 64 + fn * 16 + lr;
      bv[fn] = *(const bf16x8*)(Bs + row * 128 + s * 64 + quad * 16);
    }
#pragma unroll
    for (int fm = 0; fm < 4; ++fm)
#pragma unroll
      for (int fn = 0; fn < 4; ++fn)
        acc[fm][fn] = __builtin_amdgcn_mfma_f32_16x16x32_bf16(av[fm], bv[fn],
                                                              acc[fm][fn], 0, 0, 0);
  }

  const float th = theta[h], al = alpha[h], be = beta[h];

#pragma unroll
  for (int fm = 0; fm < 4; ++fm) {
    int prow = lm0 + wm * 64 + fm * 16 + quad * 4;
    float rs0 = 0.f, rs1 = 0.f, rs2 = 0.f, rs3 = 0.f;
#pragma unroll
    for (int fn = 0; fn < 4; ++fn) {
      int f = n0 + wn * 64 + fn * 16 + lr;
#pragma unroll
      for (int i = 0; i < 4; ++i) {
        float pf = acc[fm][fn][i];
        float pp = fmaxf(pf, 0.f);
        float pw = pf * pp;
        size_t idx = ((size_t)(h * PP + prow + i)) * FF + f;
        O1[idx] = f2bf(th * pw + al * pp - al);
        O2[idx] = f2bf(be * pw);
        if (i == 0) rs0 += pw;
        else if (i == 1) rs1 += pw;
        else if (i == 2) rs2 += pw;
        else rs3 += pw;
      }
    }
    float rs[4] = {rs0, rs1, rs2, rs3};
#pragma unroll
    for (int i = 0; i < 4; ++i) {
      float s = rs[i];
      s += __shfl_xor(s, 1);
      s += __shfl_xor(s, 2);
      s += __shfl_xor(s, 4);
      s += __shfl_xor(s, 8);
      if (lr == 0) atomicAdd(&pws[h * PP + prow + i], be * s);
    }
  }
}

// ---------------------------------------------------------------------------
// Fused main, round-6 structure + round-7 race fix + round-8 XCD placement.
//   - Q1/Q2 fragments load straight into registers (B-operands of MFMA),
//     wave->output decomposition 1x4. Compiler inserts COUNTED vmcnt waits
//     before step D -- no barrier drain of the VMEM queue.
//   - Only sF (4KB/iter) stages via global_load_lds; double-buffered, issued
//     as the NEWEST vmem so the q-register waits never drain it.
//   - Fused waitcnt+s_barrier single asm blocks (round-7 race fix): raw
//     s_barrier is not a compiler fence; a separate waitcnt leaves a
//     schedulable gap -> intermittent corruption under replay timing.
//   - Round-8 (T1): 1-D grid, in-kernel decode so all 16 b-tile blocks that
//     share one Q (p-tile, head) strip land on the SAME XCD (xcd = id%8):
//     each Q byte is HBM-fetched once chip-wide; the 15 re-reads become
//     ~200cy L2 hits, hidden under steps B+C. Each XCD gets 4 groups x 16
//     blocks = 64 = exactly 2/CU; both p-tiles of a head co-locate so f_bf
//     (0.5 MB/head) is also L2-resident.
// LDS = 8 (sF x2) + 8 + 8 = 24 KB; 2 blocks/CU.
// ---------------------------------------------------------------------------
__global__ __launch_bounds__(256, 2) void fused_main(
    const float* __restrict__ x, const unsigned short* __restrict__ f_bf,
    const unsigned short* __restrict__ Q1, const unsigned short* __restrict__ Q2,
    const float* __restrict__ pws, float* __restrict__ out) {
  // XCD-aware decode: l -> (p-tile, head, b-tile) with Q-sharers co-located.
  const int l = blockIdx.x;        // 0..511
  const int i = l >> 3;            // 0..63 within XCD
  const int g = (l & 7) * 4 + (i & 3);  // group = (p-tile, head), 0..31
  const int h = g >> 1;
  const int n0 = (g & 1) * 256;    // p tile
  const int m0 = (i >> 2) * 128;   // b tile
  const int t = threadIdx.x;
  const int wave = t >> 6, lane = t & 63;
  const int quad = lane >> 4, lr = lane & 15;
  const int key8 = lr & 7;         // swizzle key for 128B-row buffer (sF)
  const int key2 = (lr >> 1) & 3;  // swizzle key for 64B-row buffers (sX*)

  __shared__ __align__(16) char sF[2 * 4096];
  __shared__ __align__(16) char sXw[8192];
  __shared__ __align__(16) char sXp[8192];

  // Xh B-operand fragments, loaded fp32 and packed in-register.
  bf16x8 xh[2][2];
#pragma unroll
  for (int bn = 0; bn < 2; ++bn)
#pragma unroll
    for (int s = 0; s < 2; ++s) {
      int b = m0 + wave * 32 + bn * 16 + lr;
      const float* xr = x + (size_t)b * 1024 + h * 64 + s * 32 + quad * 8;
      fl4 v0 = *(const fl4*)xr;
      fl4 v1 = *(const fl4*)(xr + 4);
      union { unsigned u[4]; bf16x8 v; } cv;
      cv.u[0] = pkbf(v0.x, v0.y);
      cv.u[1] = pkbf(v0.z, v0.w);
      cv.u[2] = pkbf(v1.x, v1.y);
      cv.u[3] = pkbf(v1.z, v1.w);
      xh[bn][s] = cv.v;
    }

  // ---- hoisted (loop-invariant) LDS byte offsets ----
  int af_off[2][2];  // step B reads: sF row fm*16+lr, global chunk s*4+quad
#pragma unroll
  for (int fm = 0; fm < 2; ++fm)
#pragma unroll
    for (int s = 0; s < 2; ++s)
      af_off[fm][s] = (fm * 16 + lr) * 128 + (((s * 4 + quad) ^ key8) * 16);

  int cw_off[2][2];  // step C writes: row wave*32+bn*16+lr, chunk fm*2+(quad>>1)
#pragma unroll
  for (int fm = 0; fm < 2; ++fm)
#pragma unroll
    for (int bn = 0; bn < 2; ++bn)
      cw_off[fm][bn] = (wave * 32 + bn * 16 + lr) * 64 +
                       (((fm * 2 + (quad >> 1)) ^ key2) * 16) + (quad & 1) * 8;

  int aw_off[8];  // step D A reads: row fm*16+lr (all 128 b rows), chunk quad
#pragma unroll
  for (int fm = 0; fm < 8; ++fm)
    aw_off[fm] = (fm * 16 + lr) * 64 + ((quad ^ key2) * 16);

  // sF staging source (swizzle applied on the GLOBAL side)
  const char* srcF;
  {
    int row = t >> 3, c = t & 7, cs = c ^ (row & 7);
    srcF = (const char*)f_bf + h * 128 + (size_t)row * 2048 + cs * 16;
  }

  // per-wave Q row pointers: wave owns p = n0 + wave*64 .. +63
  const unsigned short* qrow1 =
      Q1 + (size_t)(h * PP + n0 + wave * 64 + lr) * FF + quad * 8;
  const unsigned short* qrow2 =
      Q2 + (size_t)(h * PP + n0 + wave * 64 + lr) * FF + quad * 8;

  f32x4 acc[8][4];
#pragma unroll
  for (int i2 = 0; i2 < 8; ++i2)
#pragma unroll
    for (int j = 0; j < 4; ++j) acc[i2][j] = (f32x4){0.f, 0.f, 0.f, 0.f};

  // prologue: stage sF buf0 for it=0
  gload_lds16(srcF, sF + t * 16);
  srcF += 32 * 2048;
  asm volatile("s_waitcnt vmcnt(0)\n\ts_barrier" ::: "memory");
  __builtin_amdgcn_sched_barrier(0);

  for (int it = 0; it < FF / 32; ++it) {
    const int cur = (it & 1) << 12;

    // Q fragment loads for THIS iteration (oldest VMEM of the iteration --
    // step D's compiler-inserted counted vmcnt wait covers exactly these)
    bf16x8 q1v[4], q2v[4];
#pragma unroll
    for (int fn = 0; fn < 4; ++fn) {
      q1v[fn] = *(const bf16x8*)(qrow1 + fn * (16 * FF));
      q2v[fn] = *(const bf16x8*)(qrow2 + fn * (16 * FF));
    }
    qrow1 += 32;
    qrow2 += 32;

    // next-tile F staging (newest VMEM -> stays in flight until end barrier;
    // f_bf is padded by 32 rows so the final iteration's read is in-bounds)
    gload_lds16(srcF, sF + (cur ^ 4096) + t * 16);
    srcF += 32 * 2048;

    // step B: Xf[f 0..31][b wave*32..+31]
    f32x4 xf[2][2];
#pragma unroll
    for (int fm = 0; fm < 2; ++fm)
#pragma unroll
      for (int bn = 0; bn < 2; ++bn) xf[fm][bn] = (f32x4){0.f, 0.f, 0.f, 0.f};
#pragma unroll
    for (int s = 0; s < 2; ++s)
#pragma unroll
      for (int fm = 0; fm < 2; ++fm) {
        bf16x8 af = *(const bf16x8*)(sF + cur + af_off[fm][s]);
#pragma unroll
        for (int bn = 0; bn < 2; ++bn)
          xf[fm][bn] = __builtin_amdgcn_mfma_f32_16x16x32_bf16(af, xh[bn][s],
                                                               xf[fm][bn], 0, 0, 0);
      }

    // step C: transform + pack (lane holds f = fm*16+quad*4+i, b = wave*32+bn*16+lr)
#pragma unroll
    for (int fm = 0; fm < 2; ++fm)
#pragma unroll
      for (int bn = 0; bn < 2; ++bn) {
        float v0 = xf[fm][bn][0], v1 = xf[fm][bn][1];
        float v2 = xf[fm][bn][2], v3 = xf[fm][bn][3];
        float p0 = fmaxf(v0, 0.f), p1 = fmaxf(v1, 0.f);
        float p2 = fmaxf(v2, 0.f), p3 = fmaxf(v3, 0.f);
        u32x2 w, p;
        w.x = pkbf(v0 * p0, v1 * p1);
        w.y = pkbf(v2 * p2, v3 * p3);
        p.x = pkbf(p0, p1);
        p.y = pkbf(p2, p3);
        *(u32x2*)(sXw + cw_off[fm][bn]) = w;
        *(u32x2*)(sXp + cw_off[fm][bn]) = p;
      }
    // fused wait+barrier: no scheduler gap (round-7 race fix)
    asm volatile("s_waitcnt lgkmcnt(0)\n\ts_barrier" ::: "memory");
    __builtin_amdgcn_sched_barrier(0);

    // step D: acc += Xw.Q1^T + Xp.Q2^T  (A from LDS, B from registers)
    __builtin_amdgcn_s_setprio(1);
#pragma unroll
    for (int hf = 0; hf < 2; ++hf) {
      bf16x8 aw[4], ap[4];
#pragma unroll
      for (int fm = 0; fm < 4; ++fm) {
        aw[fm] = *(const bf16x8*)(sXw + aw_off[hf * 4 + fm]);
        ap[fm] = *(const bf16x8*)(sXp + aw_off[hf * 4 + fm]);
      }
#pragma unroll
      for (int fn = 0; fn < 4; ++fn)
#pragma unroll
        for (int fm = 0; fm < 4; ++fm) {
          acc[hf * 4 + fm][fn] = __builtin_amdgcn_mfma_f32_16x16x32_bf16(
              aw[fm], q1v[fn], acc[hf * 4 + fm][fn], 0, 0, 0);
          acc[hf * 4 + fm][fn] = __builtin_amdgcn_mfma_f32_16x16x32_bf16(
              ap[fm], q2v[fn], acc[hf * 4 + fm][fn], 0, 0, 0);
        }
    }
    __builtin_amdgcn_s_setprio(0);

    // end barrier: only the tiny sF stage can still be outstanding here
    // (q loads were consumed in D); protects sXw/sXp overwrite + sF[nxt].
    asm volatile("s_waitcnt vmcnt(0)\n\ts_barrier" ::: "memory");
    __builtin_amdgcn_sched_barrier(0);
  }

  // epilogue: subtract pws, store fp32
#pragma unroll
  for (int fn = 0; fn < 4; ++fn) {
    int p = n0 + wave * 64 + fn * 16 + lr;
    float sub = pws[h * PP + p];
#pragma unroll
    for (int fm = 0; fm < 8; ++fm) {
      int brow = m0 + fm * 16 + quad * 4;
#pragma unroll
      for (int i2 = 0; i2 < 4; ++i2) {
        out[(size_t)(brow + i2) * (NH * PP) + h * PP + p] = acc[fm][fn][i2] - sub;
      }
    }
  }
}

extern "C" void kernel_launch(void* const* d_in, const int* in_sizes, int n_in,
                              void* d_out, int out_size, void* d_ws, size_t ws_size,
                              hipStream_t stream) {
  const float* x = (const float*)d_in[0];
  const float* features = (const float*)d_in[1];
  const float* prototypes = (const float*)d_in[2];
  const float* theta = (const float*)d_in[3];
  const float* alpha = (const float*)d_in[4];
  const float* beta = (const float*)d_in[5];
  float* out = (float*)d_out;

  char* ws = (char*)d_ws;
  size_t off = 0;
  auto carve = [&](size_t bytes) -> char* {
    char* p = ws + off;
    off += (bytes + 255) & ~(size_t)255;
    return p;
  };
  // f_bf padded by 32 rows: fused_main's last iteration prefetches one tile
  // past the end (data unused; keeps the main loop branch-free).
  unsigned short* f_bf = (unsigned short*)carve((size_t)(FF + 32) * 1024 * 2);
  unsigned short* p_bf = (unsigned short*)carve((size_t)PP * 1024 * 2);
  unsigned short* Q1 = (unsigned short*)carve((size_t)NH * PP * FF * 2);
  unsigned short* Q2 = (unsigned short*)carve((size_t)NH * PP * FF * 2);
  float* pws = (float*)carve((size_t)NH * PP * 4);

  const int ncvt = (FF + PP) * 1024 / 4;
  cvt_fp<<<(ncvt + 255) / 256, 256, 0, stream>>>(features, prototypes, f_bf, p_bf);
  hipMemsetAsync(pws, 0, (size_t)NH * PP * 4, stream);

  // Phase 1: prototypes -> Q1, Q2, pws
  gemm_proto<<<dim3(FF / 128, PP / 128, NH), 256, 0, stream>>>(
      p_bf, f_bf, Q1, Q2, pws, theta, alpha, beta);

  // Fused main GEMM (1-D grid, XCD-aware decode in-kernel)
  fused_main<<<dim3(512, 1, 1), 256, 0, stream>>>(
      x, f_bf, Q1, Q2, pws, out);
}